// Round 2
// baseline (2956.598 us; speedup 1.0000x reference)
//
#include <hip/hip_runtime.h>
#include <hip/hip_cooperative_groups.h>

namespace cg = cooperative_groups;

namespace {
constexpr int T_STEPS = 16;
constexpr int BROWS   = 16;                    // batch rows
constexpr int N_ELEM  = 128 * 32 * 32;         // 131072 per sample
constexpr int K_SEL   = (N_ELEM * 50) / 100;   // 65536 : k-th largest
constexpr int BPR     = 16;                    // blocks per row
constexpr int NBLK    = BROWS * BPR;           // 256
constexpr int NTHR    = 512;
constexpr int SLICE   = N_ELEM / BPR;          // 8192 elements per block
constexpr int VITERS  = SLICE / (NTHR * 4);    // 4 float4 iters per thread
constexpr int NBINS   = 2048;
constexpr int MCAP    = 8192;                  // match-list capacity per row

// workspace layout in u32 words (total ~197K words = 771 KiB)
constexpr size_t OFF_HIST  = 0;                                  // [2][BROWS][NBINS] double-buffered
constexpr size_t SZ_HIST   = (size_t)2 * BROWS * NBINS;          // 65536
constexpr size_t OFF_MCNT  = OFF_HIST + SZ_HIST;                 // [T][BROWS]
constexpr size_t SZ_MCNT   = (size_t)T_STEPS * BROWS;            // 256
constexpr size_t OFF_FBC   = OFF_MCNT + SZ_MCNT;                 // [32][BROWS] fallback counters
constexpr size_t SZ_FBC    = (size_t)32 * BROWS;                 // 512
constexpr size_t OFF_MATCH = OFF_FBC + SZ_FBC;                   // [BROWS][MCAP]
constexpr size_t SZ_MATCH  = (size_t)BROWS * MCAP;               // 131072
constexpr size_t ZERO_WORDS = OFF_MATCH;                         // memset region
} // namespace

__device__ __forceinline__ unsigned f2k(float f) {
    unsigned u = __float_as_uint(f);
    return (u & 0x80000000u) ? ~u : (u | 0x80000000u);   // monotonic: key asc <=> value asc
}
__device__ __forceinline__ float k2f(unsigned k) {
    unsigned u = (k & 0x80000000u) ? (k & 0x7fffffffu) : ~k;
    return __uint_as_float(u);
}

// Block-wide: find bin (descending key order) containing rank `rem` (1-indexed from top)
// in sh_hist[0..NBINS). Result -> sh_bcast[0]=bin, sh_bcast[1]=residual rank in bin.
__device__ void select_bin(const unsigned* sh_hist, unsigned* sh_wave,
                           unsigned* sh_bcast, unsigned rem, int tid)
{
    const int lane = tid & 63;
    const int wid  = tid >> 6;                  // 0..7
    const int b0   = NBINS - 1 - 4 * tid;       // this thread's top bin (descending chunks)
    const unsigned c0 = sh_hist[b0];
    const unsigned c1 = sh_hist[b0 - 1];
    const unsigned c2 = sh_hist[b0 - 2];
    const unsigned c3 = sh_hist[b0 - 3];
    const unsigned csum = c0 + c1 + c2 + c3;

    unsigned s = csum;                          // inclusive scan within wave
    #pragma unroll
    for (int off = 1; off < 64; off <<= 1) {
        unsigned v = __shfl_up(s, off);
        if (lane >= off) s += v;
    }
    if (lane == 63) sh_wave[wid] = s;
    __syncthreads();
    unsigned woff = 0;
    #pragma unroll
    for (int w = 0; w < 8; ++w) woff += (w < wid) ? sh_wave[w] : 0u;
    const unsigned hi = woff + s;
    const unsigned lo = hi - csum;
    if (lo < rem && rem <= hi) {                // exactly one thread
        unsigned r = rem - lo;
        int bin = b0;
        if (r > c0) { r -= c0; bin = b0 - 1;
            if (r > c1) { r -= c1; bin = b0 - 2;
                if (r > c2) { r -= c2; bin = b0 - 3; } } }
        sh_bcast[0] = (unsigned)bin;
        sh_bcast[1] = r;
    }
    __syncthreads();
}

__global__ __launch_bounds__(NTHR)
void lif_topk_coop(const float* __restrict__ x, float* __restrict__ out,
                   unsigned* __restrict__ ws)
{
    cg::grid_group grid = cg::this_grid();
    const int tid = threadIdx.x;
    const int blk = blockIdx.x;
    const int row = blk >> 4;      // batch row
    const int bir = blk & 15;      // block within row

    __shared__ float    m_lds[SLICE];       // 32 KiB membrane slice
    __shared__ unsigned sh_hist[NBINS];     // 8 KiB
    __shared__ unsigned sh_scan[NTHR];      // 2 KiB (wave sums / fallback reduce)
    __shared__ unsigned sh_bcast[2];

    unsigned* hist_all  = ws + OFF_HIST;    // [2][BROWS][NBINS]
    unsigned* mcnt_all  = ws + OFF_MCNT;    // [T][BROWS]
    unsigned* fbc       = ws + OFF_FBC;     // [32][BROWS]
    unsigned* match     = ws + OFF_MATCH + (size_t)row * MCAP;

    for (int i = tid; i < SLICE; i += NTHR) m_lds[i] = 0.0f;

    // register prefetch of x for the upcoming step
    float4 xp[VITERS];
    {
        const float* xr = x + (size_t)row * N_ELEM + (size_t)bir * SLICE;  // t = 0
        #pragma unroll
        for (int it = 0; it < VITERS; ++it)
            xp[it] = *reinterpret_cast<const float4*>(xr + it * (NTHR * 4) + tid * 4);
    }
    __syncthreads();

    for (int t = 0; t < T_STEPS; ++t) {
        unsigned* histg = hist_all + ((size_t)(t & 1) * BROWS + row) * NBINS;
        unsigned* mcnt  = mcnt_all + (size_t)t * BROWS + row;
        float*    orow  = out + ((size_t)t * BROWS + row) * N_ELEM + (size_t)bir * SLICE;

        // ---------- Phase A: leaky-integrate + per-row histogram (top 11 key bits) ----------
        for (int b = tid; b < NBINS; b += NTHR) sh_hist[b] = 0u;
        __syncthreads();
        #pragma unroll
        for (int it = 0; it < VITERS; ++it) {
            const int idx = it * (NTHR * 4) + tid * 4;
            float4 mv = *reinterpret_cast<float4*>(&m_lds[idx]);
            // 0.25*m is an exact pow2 scale -> fmaf == (0.25f*m + x) bitwise
            mv.x = fmaf(0.25f, mv.x, xp[it].x);
            mv.y = fmaf(0.25f, mv.y, xp[it].y);
            mv.z = fmaf(0.25f, mv.z, xp[it].z);
            mv.w = fmaf(0.25f, mv.w, xp[it].w);
            *reinterpret_cast<float4*>(&m_lds[idx]) = mv;
            atomicAdd(&sh_hist[f2k(mv.x) >> 21], 1u);
            atomicAdd(&sh_hist[f2k(mv.y) >> 21], 1u);
            atomicAdd(&sh_hist[f2k(mv.z) >> 21], 1u);
            atomicAdd(&sh_hist[f2k(mv.w) >> 21], 1u);
        }
        __syncthreads();
        for (int b = tid; b < NBINS; b += NTHR) {
            const unsigned v = sh_hist[b];
            if (v) atomicAdd(&histg[b], v);
        }
        grid.sync();   // SYNC 1: row histogram complete

        // ---------- Phase B1: locate candidate bin, gather own-slice matches ----------
        for (int b = tid; b < NBINS; b += NTHR) sh_hist[b] = histg[b];
        __syncthreads();
        select_bin(sh_hist, sh_scan, sh_bcast, (unsigned)K_SEL, tid);
        const unsigned cb   = sh_bcast[0];
        const unsigned rem2 = sh_bcast[1];
        #pragma unroll
        for (int it = 0; it < VITERS; ++it) {
            const int idx = it * (NTHR * 4) + tid * 4;
            float4 mv = *reinterpret_cast<float4*>(&m_lds[idx]);
            const unsigned kk0 = f2k(mv.x), kk1 = f2k(mv.y), kk2 = f2k(mv.z), kk3 = f2k(mv.w);
            if ((kk0 >> 21) == cb) { unsigned p = atomicAdd(mcnt, 1u); if (p < MCAP) match[p] = kk0; }
            if ((kk1 >> 21) == cb) { unsigned p = atomicAdd(mcnt, 1u); if (p < MCAP) match[p] = kk1; }
            if ((kk2 >> 21) == cb) { unsigned p = atomicAdd(mcnt, 1u); if (p < MCAP) match[p] = kk2; }
            if ((kk3 >> 21) == cb) { unsigned p = atomicAdd(mcnt, 1u); if (p < MCAP) match[p] = kk3; }
        }
        // prefetch next step's x while the sync + B2 hide the latency
        if (t + 1 < T_STEPS) {
            const float* xr = x + ((size_t)(t + 1) * BROWS + row) * N_ELEM + (size_t)bir * SLICE;
            #pragma unroll
            for (int it = 0; it < VITERS; ++it)
                xp[it] = *reinterpret_cast<const float4*>(xr + it * (NTHR * 4) + tid * 4);
        }
        grid.sync();   // SYNC 2: match list complete

        // ---------- Phase B2: exact threshold, spike, reset ----------
        // zero this step's global histogram buffer for reuse at t+2
        // (all reads of histg finished before SYNC 2; next writes are after SYNC 2 of t+1)
        for (int b = tid; b < NBINS; b += NTHR) histg[b] = 0u;

        // fallback decision: uniform across the grid (same global reads everywhere)
        bool fb = false;
        for (int r = 0; r < BROWS; ++r)
            fb = fb || (mcnt_all[(size_t)t * BROWS + r] > (unsigned)MCAP);

        unsigned thr_key;
        if (!fb) {
            const unsigned cnt = *mcnt;     // <= MCAP, == histogram count of bin cb
            // level 2: bits [20:10]
            for (int b = tid; b < NBINS; b += NTHR) sh_hist[b] = 0u;
            __syncthreads();
            for (unsigned i = tid; i < cnt; i += NTHR)
                atomicAdd(&sh_hist[(match[i] >> 10) & 0x7FFu], 1u);
            __syncthreads();
            select_bin(sh_hist, sh_scan, sh_bcast, rem2, tid);
            const unsigned cb2  = sh_bcast[0];
            const unsigned rem3 = sh_bcast[1];
            // level 3: bits [9:0]
            for (int b = tid; b < NBINS; b += NTHR) sh_hist[b] = 0u;
            __syncthreads();
            for (unsigned i = tid; i < cnt; i += NTHR) {
                const unsigned kk = match[i];
                if (((kk >> 10) & 0x7FFu) == cb2) atomicAdd(&sh_hist[kk & 0x3FFu], 1u);
            }
            __syncthreads();
            select_bin(sh_hist, sh_scan, sh_bcast, rem3, tid);
            thr_key = (cb << 21) | (cb2 << 10) | sh_bcast[0];
        } else {
            // bulletproof fallback: distributed 32-pass bitwise radix select over the
            // LDS-resident membranes. Grid-uniform branch -> sync counts stay aligned.
            unsigned prefix = 0u, remaining = (unsigned)K_SEL;
            for (int bit = 31; bit >= 0; --bit) {
                const unsigned mask = ~((1u << bit) - 1u);
                const unsigned want = prefix | (1u << bit);
                unsigned c = 0;
                for (int i = tid; i < SLICE; i += NTHR) {
                    const unsigned kk = f2k(m_lds[i]);
                    c += ((kk & mask) == want) ? 1u : 0u;
                }
                sh_scan[tid] = c; __syncthreads();
                for (int off = NTHR >> 1; off > 0; off >>= 1) {
                    if (tid < off) sh_scan[tid] += sh_scan[tid + off];
                    __syncthreads();
                }
                if (tid == 0 && sh_scan[0]) atomicAdd(&fbc[(size_t)bit * BROWS + row], sh_scan[0]);
                __syncthreads();
                grid.sync();
                const unsigned total = fbc[(size_t)bit * BROWS + row];  // row total, uniform
                if (total >= remaining) prefix = want; else remaining -= total;
            }
            grid.sync();   // all reads of fbc complete
            for (int b = tid; b < 32; b += NTHR) fbc[(size_t)b * BROWS + row] = 0u;  // benign dup-zero
            thr_key = prefix;
        }
        const float thr = k2f(thr_key);

        #pragma unroll
        for (int it = 0; it < VITERS; ++it) {
            const int idx = it * (NTHR * 4) + tid * 4;
            float4 mv = *reinterpret_cast<float4*>(&m_lds[idx]);
            float4 sv;
            sv.x = (mv.x >= thr) ? 1.0f : 0.0f; if (mv.x >= thr) mv.x = 0.0f;
            sv.y = (mv.y >= thr) ? 1.0f : 0.0f; if (mv.y >= thr) mv.y = 0.0f;
            sv.z = (mv.z >= thr) ? 1.0f : 0.0f; if (mv.z >= thr) mv.z = 0.0f;
            sv.w = (mv.w >= thr) ? 1.0f : 0.0f; if (mv.w >= thr) mv.w = 0.0f;
            *reinterpret_cast<float4*>(&m_lds[idx]) = mv;
            *reinterpret_cast<float4*>(orow + idx) = sv;
        }
        // no grid sync needed here: SYNC1(t+1) orders this step's B2 against t+1's B1 reads
    }
}

extern "C" void kernel_launch(void* const* d_in, const int* in_sizes, int n_in,
                              void* d_out, int out_size, void* d_ws, size_t ws_size,
                              hipStream_t stream)
{
    (void)in_sizes; (void)n_in; (void)out_size; (void)ws_size;
    const float* x  = (const float*)d_in[0];
    float*       o  = (float*)d_out;
    unsigned*    ws = (unsigned*)d_ws;

    // zero histograms + match-counts + fallback counters (contiguous at ws start)
    hipMemsetAsync(d_ws, 0, ZERO_WORDS * sizeof(unsigned), stream);

    void* args[] = { (void*)&x, (void*)&o, (void*)&ws };
    hipLaunchCooperativeKernel((const void*)lif_topk_coop,
                               dim3(NBLK), dim3(NTHR), args, 0, stream);
}